// Round 2
// baseline (192.608 us; speedup 1.0000x reference)
//
#include <hip/hip_runtime.h>

#define DD 32
#define NSTEP 391
#define NB 128
#define NSITES 784

// Broadcast value held by group-lane l to all lanes of each 32-lane half.
// ds_swizzle BitMode: src = ((lane & and) | or) ^ xor; offset = xor<<10|or<<5|and.
#define SWZ(ci, l) __int_as_float(__builtin_amdgcn_ds_swizzle((ci), ((l) << 5)))

#define SWL(l, acc) acc = fmaf(SWZ(ci, l), av[l], acc);
#define DOT32                                                        \
    SWL(0, s0)  SWL(1, s1)  SWL(2, s2)  SWL(3, s3)                   \
    SWL(4, s0)  SWL(5, s1)  SWL(6, s2)  SWL(7, s3)                   \
    SWL(8, s0)  SWL(9, s1)  SWL(10, s2) SWL(11, s3)                  \
    SWL(12, s0) SWL(13, s1) SWL(14, s2) SWL(15, s3)                  \
    SWL(16, s0) SWL(17, s1) SWL(18, s2) SWL(19, s3)                  \
    SWL(20, s0) SWL(21, s1) SWL(22, s2) SWL(23, s3)                  \
    SWL(24, s0) SWL(25, s1) SWL(26, s2) SWL(27, s3)                  \
    SWL(28, s0) SWL(29, s1) SWL(30, s2) SWL(31, s3)

__device__ __forceinline__ void loadav(float* av, const float* p) {
    #pragma unroll
    for (int i = 0; i < 8; ++i) {
        float4 v = ((const float4*)p)[i];
        av[4 * i + 0] = v.x; av[4 * i + 1] = v.y;
        av[4 * i + 2] = v.z; av[4 * i + 3] = v.w;
    }
}

__device__ __forceinline__ float dot_step(float cv, const float* av, float xc) {
    int ci = __float_as_int(cv);
    float s0 = 0.f, s1 = 0.f, s2 = 0.f, s3 = 0.f;
    DOT32
    float dot = (s0 + s1) + (s2 + s3);
    float val = xc * dot;
    val += __shfl_xor(val, 32);   // combine the two p-halves
    return val;
}

// cores_left (391,32,2,32)[n][l][h][r] -> At (391,2,32,32)[n][h][r][l]
__global__ __launch_bounds__(256) void transpose_left(
    const float* __restrict__ in, float* __restrict__ out) {
    const int n = blockIdx.x;
    const float* pin = in + n * 2048;
    float* pout = out + n * 2048;
    for (int e = threadIdx.x; e < 2048; e += 256) {
        int l = e >> 6;
        int h = (e >> 5) & 1;
        int r = e & 31;
        pout[h * 1024 + r * 32 + l] = pin[e];
    }
}

__global__ __launch_bounds__(64) void mps_chains(
    const float* __restrict__ x,       // (B, 784, 2)
    const float* __restrict__ a0,      // (32, 2)
    const float* __restrict__ At,      // transposed left cores (391,2,32,32)
    const float* __restrict__ coresR,  // (391, 32, 2, 32)
    const float* __restrict__ aend,    // (32, 2)
    float* __restrict__ wsL,           // (B, 32)
    float* __restrict__ wsR)           // (B, 32)
{
    __shared__ float2 xsh[392];
    const int tid  = threadIdx.x;
    const int bid  = blockIdx.x;
    const int b    = bid >> 1;
    const int side = bid & 1;
    const int h    = tid >> 5;   // p-component for this half-wave
    const int r    = tid & 31;   // output index

    const float2* xb = (const float2*)x + b * NSITES;
    float avA[32], avB[32];

    if (side == 0) {
        // left chain: c_new[r] = sum_l c[l] * (x0*A[l,0,r] + x1*A[l,1,r])
        for (int i = tid; i < 392; i += 64) xsh[i] = xb[i];
        __syncthreads();

        float2 xs0 = xsh[0];
        float cv = fmaf(a0[r * 2], xs0.x, a0[r * 2 + 1] * xs0.y);

        const float* p = At + h * 1024 + r * 32;   // + n*2048, 32 contiguous
        loadav(avA, p);                             // step 0
        int n = 0;
        for (; n + 2 <= NSTEP - 1; n += 2) {
            loadav(avB, p + (n + 1) * 2048);
            float2 xs = xsh[n + 1];
            cv = dot_step(cv, avA, h ? xs.y : xs.x);
            loadav(avA, p + (n + 2) * 2048);
            xs = xsh[n + 2];
            cv = dot_step(cv, avB, h ? xs.y : xs.x);
        }
        {   // n == 390
            float2 xs = xsh[391];
            cv = dot_step(cv, avA, h ? xs.y : xs.x);
        }
        if (tid < 32) wsL[b * DD + r] = cv;
    } else {
        // right chain (reverse): c_new[l] = sum_r M[l,r] * c[r]
        for (int i = tid; i < 392; i += 64) xsh[i] = xb[392 + i];
        __syncthreads();

        float2 xe = xsh[391];
        float cv = fmaf(aend[r * 2], xe.x, aend[r * 2 + 1] * xe.y);

        const float* p = coresR + r * 64 + h * 32;  // + n*2048, 32 contiguous
        loadav(avA, p + 390 * 2048);
        int n = 390;
        for (; n - 2 >= 0; n -= 2) {
            loadav(avB, p + (n - 1) * 2048);
            float2 xs = xsh[n];
            cv = dot_step(cv, avA, h ? xs.y : xs.x);
            loadav(avA, p + (n - 2) * 2048);
            xs = xsh[n - 1];
            cv = dot_step(cv, avB, h ? xs.y : xs.x);
        }
        {   // n == 0
            float2 xs = xsh[0];
            cv = dot_step(cv, avA, h ? xs.y : xs.x);
        }
        if (tid < 32) wsR[b * DD + r] = cv;
    }
}

__global__ __launch_bounds__(64) void mps_final(
    const float* __restrict__ wsL, const float* __restrict__ wsR,
    const float* __restrict__ mid,  // core_mid (32, 10, 32)
    float* __restrict__ out)        // (B, 10)
{
    const int b = blockIdx.x;
    const int a = threadIdx.x & 31;
    float pa = wsL[b * 32 + a] * wsR[b * 32 + a];
    #pragma unroll
    for (int c = 0; c < 10; ++c) {
        float s = pa * mid[a * 320 + c * 32 + a];   // mid_diag[a,c] = core_mid[a,c,a]
        s += __shfl_xor(s, 16, 32);
        s += __shfl_xor(s, 8, 32);
        s += __shfl_xor(s, 4, 32);
        s += __shfl_xor(s, 2, 32);
        s += __shfl_xor(s, 1, 32);
        if (threadIdx.x == 0) out[b * 10 + c] = s;
    }
}

extern "C" void kernel_launch(void* const* d_in, const int* in_sizes, int n_in,
                              void* d_out, int out_size, void* d_ws, size_t ws_size,
                              hipStream_t stream) {
    const float* x      = (const float*)d_in[0];
    const float* a0     = (const float*)d_in[1];
    const float* coresL = (const float*)d_in[2];
    const float* mid    = (const float*)d_in[3];
    const float* coresR = (const float*)d_in[4];
    const float* aend   = (const float*)d_in[5];

    float* At  = (float*)d_ws;                 // 391*2048 floats = 3.2 MB
    float* wsL = At + NSTEP * 2048;            // 128*32
    float* wsR = wsL + NB * DD;                // 128*32
    float* out = (float*)d_out;

    transpose_left<<<dim3(NSTEP), dim3(256), 0, stream>>>(coresL, At);
    mps_chains<<<dim3(2 * NB), dim3(64), 0, stream>>>(x, a0, At, coresR, aend, wsL, wsR);
    mps_final<<<dim3(NB), dim3(64), 0, stream>>>(wsL, wsR, mid, out);
}

// Round 3
// 192.177 us; speedup vs baseline: 1.0022x; 1.0022x over previous
//
#include <hip/hip_runtime.h>

#define DD 32
#define NSTEP 391
#define NB 128
#define NSITES 784
#define PDEPTH 6          // LDS ring depth (tiles)
#define TILE 2048         // floats per tile (32x2x32)

typedef const __attribute__((address_space(1))) void* gas_ptr;
typedef __attribute__((address_space(3))) void* las_ptr;

// wait until at most N vector-memory ops outstanding
#define WAITVM_(N) asm volatile("s_waitcnt vmcnt(" #N ")" ::: "memory")
#define WAITVM(N) WAITVM_(N)
#define VM_STEADY 40      // 8 loads * (PDEPTH-1) tiles allowed in flight

// broadcast c[l] (held by lane l) to all lanes via readlane -> SGPR
#define RL(v, l) __int_as_float(__builtin_amdgcn_readlane(__float_as_int(v), (l)))

// Issue one 8KB tile global->LDS, linear LDS dest, source pre-swizzled so that
// LDS[row][chunk] = Global[row][chunk ^ (row&7)]  (row = 128B, chunk = 16B).
__device__ __forceinline__ void issue_tile(const float* g, float* slot, int laneSrc) {
    #pragma unroll
    for (int i = 0; i < 8; ++i)
        __builtin_amdgcn_global_load_lds(
            (gas_ptr)((const char*)g + i * 1024 + laneSrc),
            (las_ptr)((char*)slot + i * 1024), 16, 0, 0);
}

// one chain step: av = row of tile (de-swizzled), dot with broadcast c, x-scale,
// combine the two p-halves.
template <int DIR>
__device__ __forceinline__ float do_step(const float* slotbase, const float2* xsh,
                                         float cv, int k, int h, int row, int rk) {
    const float* sb = slotbase + row * 32;
    float av[32];
    #pragma unroll
    for (int c = 0; c < 8; ++c) {
        float4 v = *(const float4*)(sb + ((c ^ rk) << 2));
        av[4 * c + 0] = v.x; av[4 * c + 1] = v.y;
        av[4 * c + 2] = v.z; av[4 * c + 3] = v.w;
    }
    const int t = DIR ? (390 - k) : k;
    float2 xs = xsh[DIR ? t : (t + 1)];
    float xc = h ? xs.y : xs.x;
    float s0 = 0.f, s1 = 0.f, s2 = 0.f, s3 = 0.f;
    #pragma unroll
    for (int l = 0; l < 32; l += 4) {
        s0 = fmaf(RL(cv, l + 0), av[l + 0], s0);
        s1 = fmaf(RL(cv, l + 1), av[l + 1], s1);
        s2 = fmaf(RL(cv, l + 2), av[l + 2], s2);
        s3 = fmaf(RL(cv, l + 3), av[l + 3], s3);
    }
    float val = xc * ((s0 + s1) + (s2 + s3));
    val += __shfl_xor(val, 32);   // combine h=0/h=1 halves
    return val;
}

template <int DIR>
__device__ __forceinline__ float run_chain(const float* tiles, float* ring,
                                           const float2* xsh, float cv,
                                           int h, int row, int laneSrc) {
    const int rk = row & 7;
    #pragma unroll
    for (int kp = 0; kp < PDEPTH - 1; ++kp) {          // prologue: 5 tiles
        int t = DIR ? (390 - kp) : kp;
        issue_tile(tiles + t * TILE, ring + kp * TILE, laneSrc);
    }
    int slot_proc = 0, slot_pref = PDEPTH - 1;
    for (int k = 0; k < NSTEP - (PDEPTH - 1); ++k) {
        int tp = DIR ? (390 - (k + PDEPTH - 1)) : (k + PDEPTH - 1);
        issue_tile(tiles + tp * TILE, ring + slot_pref * TILE, laneSrc);
        WAITVM(VM_STEADY);                              // tile k landed
        __builtin_amdgcn_sched_barrier(0);
        cv = do_step<DIR>(ring + slot_proc * TILE, xsh, cv, k, h, row, rk);
        if (++slot_proc == PDEPTH) slot_proc = 0;
        if (++slot_pref == PDEPTH) slot_pref = 0;
    }
    WAITVM(0);                                          // drain remaining tiles
    __builtin_amdgcn_sched_barrier(0);
    for (int k = NSTEP - (PDEPTH - 1); k < NSTEP; ++k) {
        cv = do_step<DIR>(ring + slot_proc * TILE, xsh, cv, k, h, row, rk);
        if (++slot_proc == PDEPTH) slot_proc = 0;
    }
    return cv;
}

// cores_left (391,32,2,32)[n][l][h][r] -> At (391,2,32,32)[n][h][r][l]
// LDS-tiled so both global sides are coalesced; +1/32 pad kills read conflicts.
__global__ __launch_bounds__(256) void transpose_left(
    const float* __restrict__ in, float* __restrict__ out) {
    __shared__ float t[TILE + 64];
    const int n = blockIdx.x;
    const float* pin = in + n * TILE;
    float* pout = out + n * TILE;
    for (int e = threadIdx.x; e < TILE; e += 256) t[e + (e >> 5)] = pin[e];
    __syncthreads();
    for (int o = threadIdx.x; o < TILE; o += 256) {
        int hh = o >> 10, rr = (o >> 5) & 31, ll = o & 31;
        int src = ll * 64 + hh * 32 + rr;
        pout[o] = t[src + (src >> 5)];
    }
}

__global__ __launch_bounds__(64) void mps_chains(
    const float* __restrict__ x,       // (B, 784, 2)
    const float* __restrict__ a0,      // (32, 2)
    const float* __restrict__ At,      // (391, 2, 32, 32) transposed left
    const float* __restrict__ coresR,  // (391, 32, 2, 32)
    const float* __restrict__ aend,    // (32, 2)
    float* __restrict__ wsL, float* __restrict__ wsR) {
    __shared__ float ring[PDEPTH * TILE];   // 48 KB
    __shared__ float2 xsh[392];
    const int tid  = threadIdx.x;
    const int b    = blockIdx.x >> 1;
    const int side = blockIdx.x & 1;
    const int h    = tid >> 5;
    const int r    = tid & 31;
    // glds source swizzle: lane j covers LDS (row = 8i + (j>>3), chunk = j&7)
    const int laneSrc = ((tid >> 3) << 7) + (((tid & 7) ^ (tid >> 3)) << 4);

    const float2* xb = (const float2*)x + b * NSITES + (side ? 392 : 0);
    for (int i = tid; i < 392; i += 64) xsh[i] = xb[i];
    __syncthreads();

    if (side == 0) {
        float2 xs0 = xsh[0];
        float cv = fmaf(a0[r * 2], xs0.x, a0[r * 2 + 1] * xs0.y);
        cv = run_chain<0>(At, ring, xsh, cv, h, h * 32 + r, laneSrc);
        if (tid < 32) wsL[b * DD + r] = cv;
    } else {
        float2 xe = xsh[391];
        float cv = fmaf(aend[r * 2], xe.x, aend[r * 2 + 1] * xe.y);
        cv = run_chain<1>(coresR, ring, xsh, cv, h, 2 * r + h, laneSrc);
        if (tid < 32) wsR[b * DD + r] = cv;
    }
}

__global__ __launch_bounds__(64) void mps_final(
    const float* __restrict__ wsL, const float* __restrict__ wsR,
    const float* __restrict__ mid,  // core_mid (32, 10, 32)
    float* __restrict__ out) {      // (B, 10)
    const int b = blockIdx.x;
    const int a = threadIdx.x & 31;
    float pa = wsL[b * 32 + a] * wsR[b * 32 + a];
    #pragma unroll
    for (int c = 0; c < 10; ++c) {
        float s = pa * mid[a * 320 + c * 32 + a];   // mid_diag[a,c] = core_mid[a,c,a]
        s += __shfl_xor(s, 16, 32);
        s += __shfl_xor(s, 8, 32);
        s += __shfl_xor(s, 4, 32);
        s += __shfl_xor(s, 2, 32);
        s += __shfl_xor(s, 1, 32);
        if (threadIdx.x == 0) out[b * 10 + c] = s;
    }
}

extern "C" void kernel_launch(void* const* d_in, const int* in_sizes, int n_in,
                              void* d_out, int out_size, void* d_ws, size_t ws_size,
                              hipStream_t stream) {
    const float* x      = (const float*)d_in[0];
    const float* a0     = (const float*)d_in[1];
    const float* coresL = (const float*)d_in[2];
    const float* mid    = (const float*)d_in[3];
    const float* coresR = (const float*)d_in[4];
    const float* aend   = (const float*)d_in[5];

    float* At  = (float*)d_ws;                 // 391*2048 floats = 3.2 MB
    float* wsL = At + NSTEP * TILE;
    float* wsR = wsL + NB * DD;
    float* out = (float*)d_out;

    transpose_left<<<dim3(NSTEP), dim3(256), 0, stream>>>(coresL, At);
    mps_chains<<<dim3(2 * NB), dim3(64), 0, stream>>>(x, a0, At, coresR, aend, wsL, wsR);
    mps_final<<<dim3(NB), dim3(64), 0, stream>>>(wsL, wsR, mid, out);
}

// Round 4
// 121.551 us; speedup vs baseline: 1.5846x; 1.5810x over previous
//
#include <hip/hip_runtime.h>

#define NSTEP 391
#define NB 128
#define NGRP 16

typedef __attribute__((ext_vector_type(8))) short s8v;      // 8 bf16 (4 VGPR)
typedef __attribute__((ext_vector_type(16))) float f32x16;  // MFMA C/D

union I4S8 { int4 i; s8v v; };
union W4S8 { int w[4]; s8v v; };

__device__ __forceinline__ int pack_hi(float a, float b) {
    // word = [bf16(b)|bf16(a)], truncation-rounded (top 16 bits of each f32)
    return (__float_as_int(b) & 0xffff0000) | ((unsigned)__float_as_int(a) >> 16);
}
__device__ __forceinline__ float trunc_bf(float a) {
    return __int_as_float(__float_as_int(a) & 0xffff0000);
}
__device__ __forceinline__ int cvtpk(float a, float b) {
    int r;
    asm("v_cvt_pk_bf16_f32 %0, %1, %2" : "=v"(r) : "v"(a), "v"(b));
    return r;
}

// ---- prep: split A0/A1 of both sides into bf16 hi/lo MFMA A-fragments ----
// frag layout per (side,t,lane): 8 frags x 4 dwords; f = part*4 + p*2 + j
// (part: 0=hi 1=lo; p: which weight matrix; j: k-half 0..15 / 16..31)
// element kk of frag: k = 16j + 8*(lane>>5) + kk ; A-row (left) / A-col (right) = lane&31
// right side stores the TRANSPOSED matrix (we accumulate P = M'^T * P).
__global__ __launch_bounds__(256) void prep(
    const float* __restrict__ coresL, const float* __restrict__ coresR,
    int* __restrict__ aprep) {
    const int bid = blockIdx.x;            // 0..781
    const int side = bid >= NSTEP;
    const int t = bid - side * NSTEP;
    const float* st = (side ? coresR : coresL) + t * 2048;
    int* out = aprep + (size_t)(side * NSTEP + t) * 2048;
    for (int q2 = threadIdx.x; q2 < 2048; q2 += 256) {
        const int lane = q2 >> 5, q = q2 & 31;
        const int f = q >> 2, w = q & 3;
        const int part = f >> 2, p = (f >> 1) & 1, j = f & 1;
        const int h = lane >> 5, c = lane & 31;
        const int k0 = j * 16 + h * 8 + w * 2;
        float e0, e1;
        if (!side) { e0 = st[c * 64 + p * 32 + k0];  e1 = st[c * 64 + p * 32 + k0 + 1]; }
        else       { e0 = st[k0 * 64 + p * 32 + c];  e1 = st[(k0 + 1) * 64 + p * 32 + c]; }
        int word;
        if (part == 0) word = pack_hi(e0, e1);
        else           word = pack_hi(e0 - trunc_bf(e0), e1 - trunc_bf(e1));
        out[q2] = word;
    }
}

// ---- stage 1: per (side,b,group) wave computes the group transfer product ----
// left:  Q = M_a * ... * M_b        (accumulate Q <- M_t*Q, t = b..a)
// right: P = (M_a*...*M_b)^T = M_b^T*...*M_a^T  (accumulate P <- M_t^T*P, t = a..b)
// Q kept in f32 C-layout: lane(h,col): d[r] = Q[(r&3)+8*(r>>2)+4h][col]
__global__ __launch_bounds__(256, 3) void stage1(
    const float* __restrict__ x, const int* __restrict__ aprep,
    float* __restrict__ qws) {
    const int w = blockIdx.x * 4 + (threadIdx.x >> 6);   // task 0..4095
    const int lane = threadIdx.x & 63;
    const int side = w >> 11;
    const int b = (w >> 4) & 127;
    const int g = w & 15;
    const int a = g * 24 + (g < 7 ? g : 7);
    const int len = 24 + (g < 7 ? 1 : 0);
    const int h = lane >> 5, col = lane & 31;
    const bool h0 = (h == 0);

    float d[16];
    #pragma unroll
    for (int r = 0; r < 16; ++r)
        d[r] = (((r & 3) + 8 * (r >> 2) + 4 * h) == col) ? 1.0f : 0.0f;   // Q = I

    const float2* xb = (const float2*)x + b * 784 + (side ? 392 : 1);

    for (int i = 0; i < len; ++i) {
        const int t = side ? (a + i) : (a + len - 1 - i);
        const float2 xv = xb[t];
        const int4* ap = (const int4*)(aprep + ((size_t)(side * NSTEP + t) * 64 + lane) * 32);
        I4S8 fr[8];
        #pragma unroll
        for (int f = 0; f < 8; ++f) fr[f].i = ap[f];

        // ---- D(C-layout f32) -> B-operand bf16 hi/lo fragments ----
        float sx[16];
        #pragma unroll
        for (int r = 0; r < 16; ++r) sx[r] = __shfl_xor(d[r], 32);
        float B1[8], B2[8];   // B1: Q rows 8h+kk ; B2: Q rows 16+8h+kk
        #pragma unroll
        for (int m = 0; m < 4; ++m) {
            B1[m]     = h0 ? d[m]      : sx[4 + m];
            B1[4 + m] = h0 ? sx[m]     : d[4 + m];
            B2[m]     = h0 ? d[8 + m]  : sx[12 + m];
            B2[4 + m] = h0 ? sx[8 + m] : d[12 + m];
        }
        W4S8 b1h, b1l, b2h, b2l;
        #pragma unroll
        for (int ww = 0; ww < 4; ++ww) {
            b1h.w[ww] = pack_hi(B1[2 * ww], B1[2 * ww + 1]);
            b2h.w[ww] = pack_hi(B2[2 * ww], B2[2 * ww + 1]);
            b1l.w[ww] = cvtpk(B1[2 * ww] - trunc_bf(B1[2 * ww]),
                              B1[2 * ww + 1] - trunc_bf(B1[2 * ww + 1]));
            b2l.w[ww] = cvtpk(B2[2 * ww] - trunc_bf(B2[2 * ww]),
                              B2[2 * ww + 1] - trunc_bf(B2[2 * ww + 1]));
        }
        // ---- acc0 = A0*Q, acc1 = A1*Q (split-bf16: hh + hl + lh) ----
        f32x16 acc0 = {0}; f32x16 acc1 = {0};
        acc0 = __builtin_amdgcn_mfma_f32_32x32x16_bf16(fr[0].v, b1h.v, acc0, 0, 0, 0);
        acc0 = __builtin_amdgcn_mfma_f32_32x32x16_bf16(fr[1].v, b2h.v, acc0, 0, 0, 0);
        acc0 = __builtin_amdgcn_mfma_f32_32x32x16_bf16(fr[0].v, b1l.v, acc0, 0, 0, 0);
        acc0 = __builtin_amdgcn_mfma_f32_32x32x16_bf16(fr[1].v, b2l.v, acc0, 0, 0, 0);
        acc0 = __builtin_amdgcn_mfma_f32_32x32x16_bf16(fr[4].v, b1h.v, acc0, 0, 0, 0);
        acc0 = __builtin_amdgcn_mfma_f32_32x32x16_bf16(fr[5].v, b2h.v, acc0, 0, 0, 0);
        acc1 = __builtin_amdgcn_mfma_f32_32x32x16_bf16(fr[2].v, b1h.v, acc1, 0, 0, 0);
        acc1 = __builtin_amdgcn_mfma_f32_32x32x16_bf16(fr[3].v, b2h.v, acc1, 0, 0, 0);
        acc1 = __builtin_amdgcn_mfma_f32_32x32x16_bf16(fr[2].v, b1l.v, acc1, 0, 0, 0);
        acc1 = __builtin_amdgcn_mfma_f32_32x32x16_bf16(fr[3].v, b2l.v, acc1, 0, 0, 0);
        acc1 = __builtin_amdgcn_mfma_f32_32x32x16_bf16(fr[6].v, b1h.v, acc1, 0, 0, 0);
        acc1 = __builtin_amdgcn_mfma_f32_32x32x16_bf16(fr[7].v, b2h.v, acc1, 0, 0, 0);
        // M = x0*A0 + x1*A1  =>  Q_new = x0*acc0 + x1*acc1
        #pragma unroll
        for (int r = 0; r < 16; ++r) d[r] = xv.x * acc0[r] + xv.y * acc1[r];
    }
    float4* qout = (float4*)(qws + (size_t)w * 1024 + lane * 16);
    qout[0] = make_float4(d[0], d[1], d[2], d[3]);
    qout[1] = make_float4(d[4], d[5], d[6], d[7]);
    qout[2] = make_float4(d[8], d[9], d[10], d[11]);
    qout[3] = make_float4(d[12], d[13], d[14], d[15]);
}

// ---- stage 2: v^T through the G group matrices (both sides are row-vector chains) ----
__global__ __launch_bounds__(64) void stage2(
    const float* __restrict__ x, const float* __restrict__ a0,
    const float* __restrict__ aend, const float* __restrict__ qws,
    float* __restrict__ lw, float* __restrict__ rw) {
    const int b = blockIdx.x >> 1, side = blockIdx.x & 1;
    const int lane = threadIdx.x;
    const int j = lane >> 5, c = lane & 31;
    const float2* xb = (const float2*)x + b * 784;
    float v;
    if (side == 0) { float2 x0 = xb[0];   v = fmaf(a0[c * 2], x0.x, a0[c * 2 + 1] * x0.y); }
    else           { float2 xe = xb[783]; v = fmaf(aend[c * 2], xe.x, aend[c * 2 + 1] * xe.y); }
    for (int i = 0; i < NGRP; ++i) {
        const int g = side ? (NGRP - 1 - i) : i;
        const int task = side * 2048 + b * 16 + g;
        const float4* qp = (const float4*)(qws + (size_t)task * 1024 + (j * 32 + c) * 16);
        float q[16];
        #pragma unroll
        for (int u = 0; u < 4; ++u) {
            float4 t4 = qp[u];
            q[4 * u] = t4.x; q[4 * u + 1] = t4.y; q[4 * u + 2] = t4.z; q[4 * u + 3] = t4.w;
        }
        float s0 = 0.f, s1 = 0.f, s2 = 0.f, s3 = 0.f;
        #pragma unroll
        for (int r = 0; r < 16; r += 4) {
            s0 = fmaf(__shfl(v, (0) + 8 * (r >> 2) + 4 * j, 64), q[r + 0], s0);
            s1 = fmaf(__shfl(v, (1) + 8 * (r >> 2) + 4 * j, 64), q[r + 1], s1);
            s2 = fmaf(__shfl(v, (2) + 8 * (r >> 2) + 4 * j, 64), q[r + 2], s2);
            s3 = fmaf(__shfl(v, (3) + 8 * (r >> 2) + 4 * j, 64), q[r + 3], s3);
        }
        float s = (s0 + s1) + (s2 + s3);
        s += __shfl_xor(s, 32);
        v = s;
    }
    if (lane < 32) { (side ? rw : lw)[b * 32 + c] = v; }
}

__global__ __launch_bounds__(64) void mps_final(
    const float* __restrict__ lw, const float* __restrict__ rw,
    const float* __restrict__ mid,  // core_mid (32, 10, 32)
    float* __restrict__ out) {      // (B, 10)
    const int b = blockIdx.x;
    const int a = threadIdx.x & 31;
    float pa = lw[b * 32 + a] * rw[b * 32 + a];
    #pragma unroll
    for (int c = 0; c < 10; ++c) {
        float s = pa * mid[a * 320 + c * 32 + a];   // mid_diag[a,c] = core_mid[a,c,a]
        s += __shfl_xor(s, 16, 32);
        s += __shfl_xor(s, 8, 32);
        s += __shfl_xor(s, 4, 32);
        s += __shfl_xor(s, 2, 32);
        s += __shfl_xor(s, 1, 32);
        if (threadIdx.x == 0) out[b * 10 + c] = s;
    }
}

extern "C" void kernel_launch(void* const* d_in, const int* in_sizes, int n_in,
                              void* d_out, int out_size, void* d_ws, size_t ws_size,
                              hipStream_t stream) {
    const float* x      = (const float*)d_in[0];
    const float* a0     = (const float*)d_in[1];
    const float* coresL = (const float*)d_in[2];
    const float* mid    = (const float*)d_in[3];
    const float* coresR = (const float*)d_in[4];
    const float* aend   = (const float*)d_in[5];

    int*   aprep = (int*)d_ws;                           // 2*391*2048 dwords = 6.4 MB
    float* qws   = (float*)d_ws + 2 * NSTEP * 2048;      // 4096*1024 f32    = 16 MB
    float* lw    = qws + 4096 * 1024;                    // 128*32
    float* rw    = lw + NB * 32;                         // 128*32
    float* out   = (float*)d_out;

    prep<<<dim3(2 * NSTEP), dim3(256), 0, stream>>>(coresL, coresR, aprep);
    stage1<<<dim3(1024), dim3(256), 0, stream>>>(x, aprep, qws);
    stage2<<<dim3(2 * NB), dim3(64), 0, stream>>>(x, a0, aend, qws, lw, rw);
    mps_final<<<dim3(NB), dim3(64), 0, stream>>>(lw, rw, mid, out);
}

// Round 6
// 88.372 us; speedup vs baseline: 2.1795x; 1.3754x over previous
//
#include <hip/hip_runtime.h>

#define NSTEP 391
#define NB 128
#define NGRP 16

typedef __attribute__((ext_vector_type(8))) short s8v;      // 8 bf16 (4 VGPR)
typedef __attribute__((ext_vector_type(16))) float f32x16;  // MFMA C/D

typedef const __attribute__((address_space(1))) void* gas_ptr;
typedef __attribute__((address_space(3))) void* las_ptr;

union I4S8 { int4 i; s8v v; };
union W4S8 { int w[4]; s8v v; };

#define WAITVM(N) do { asm volatile("s_waitcnt vmcnt(" #N ")" ::: "memory"); \
                       __builtin_amdgcn_sched_barrier(0); } while (0)
#define LGKM0     do { asm volatile("s_waitcnt lgkmcnt(0)" ::: "memory");   \
                       __builtin_amdgcn_sched_barrier(0); } while (0)

__device__ __forceinline__ int pack_hi(float a, float b) {
    // word = [bf16(b)|bf16(a)], truncation
    return (__float_as_int(b) & 0xffff0000) | ((unsigned)__float_as_int(a) >> 16);
}
__device__ __forceinline__ float trunc_bf(float a) {
    return __int_as_float(__float_as_int(a) & 0xffff0000);
}
__device__ __forceinline__ int cvtpk(float a, float b) {  // [bf16(b)|bf16(a)] RNE
    int r;
    asm("v_cvt_pk_bf16_f32 %0, %1, %2" : "=v"(r) : "v"(a), "v"(b));
    return r;
}

// ---- prep: split A0/A1 into bf16 hi/lo MFMA A-fragments, frag-major tiles ----
// tile[t] (2048 ints): [f:8][lane:64][w:4]  -> frag f is a contiguous 1KB block
// f = part*4 + p*2 + j ; word w holds elements k0 = j*16 + h*8 + w*2 (lo) and
// k0+1 (hi); h = lane>>5. left stores A[row=lane&31][k]; right stores A^T.
__global__ __launch_bounds__(256) void prep(
    const float* __restrict__ coresL, const float* __restrict__ coresR,
    int* __restrict__ aprep) {
    const int bid = blockIdx.x;            // 0..781
    const int side = bid >= NSTEP;
    const int t = bid - side * NSTEP;
    const float* st = (side ? coresR : coresL) + t * 2048;
    int* out = aprep + (size_t)(side * NSTEP + t) * 2048;
    for (int o = threadIdx.x; o < 2048; o += 256) {
        const int f = o >> 8, lane = (o >> 2) & 63, w = o & 3;
        const int part = f >> 2, p = (f >> 1) & 1, j = f & 1;
        const int h = lane >> 5, c = lane & 31;
        const int k0 = j * 16 + h * 8 + w * 2;
        float e0, e1;
        if (!side) { e0 = st[c * 64 + p * 32 + k0];  e1 = st[c * 64 + p * 32 + k0 + 1]; }
        else       { e0 = st[k0 * 64 + p * 32 + c];  e1 = st[(k0 + 1) * 64 + p * 32 + c]; }
        out[o] = (part == 0) ? pack_hi(e0, e1)
                             : pack_hi(e0 - trunc_bf(e0), e1 - trunc_bf(e1));
    }
}

// Build B-operand fragments from Q (C-layout f32 d[16]).  (proven in R4)
__device__ __forceinline__ void bpack(const float* d, bool h0, W4S8& b1h, W4S8& b2h,
                                      W4S8& b1l, W4S8& b2l) {
    float sx[16];
    #pragma unroll
    for (int r = 0; r < 16; ++r) sx[r] = __shfl_xor(d[r], 32);
    float B1[8], B2[8];
    #pragma unroll
    for (int m = 0; m < 4; ++m) {
        B1[m]     = h0 ? d[m]      : sx[4 + m];
        B1[4 + m] = h0 ? sx[m]     : d[4 + m];
        B2[m]     = h0 ? d[8 + m]  : sx[12 + m];
        B2[4 + m] = h0 ? sx[8 + m] : d[12 + m];
    }
    #pragma unroll
    for (int ww = 0; ww < 4; ++ww) {
        b1h.w[ww] = pack_hi(B1[2 * ww], B1[2 * ww + 1]);
        b2h.w[ww] = pack_hi(B2[2 * ww], B2[2 * ww + 1]);
        b1l.w[ww] = cvtpk(B1[2 * ww] - trunc_bf(B1[2 * ww]),
                          B1[2 * ww + 1] - trunc_bf(B1[2 * ww + 1]));
        b2l.w[ww] = cvtpk(B2[2 * ww] - trunc_bf(B2[2 * ww]),
                          B2[2 * ww + 1] - trunc_bf(B2[2 * ww + 1]));
    }
}

__device__ __forceinline__ void mstep(float* d, const I4S8* fr,
                                      const W4S8& b1h, const W4S8& b2h,
                                      const W4S8& b1l, const W4S8& b2l, float2 xv) {
    f32x16 acc0 = {}; f32x16 acc1 = {};
    acc0 = __builtin_amdgcn_mfma_f32_32x32x16_bf16(fr[0].v, b1h.v, acc0, 0, 0, 0);
    acc1 = __builtin_amdgcn_mfma_f32_32x32x16_bf16(fr[2].v, b1h.v, acc1, 0, 0, 0);
    acc0 = __builtin_amdgcn_mfma_f32_32x32x16_bf16(fr[1].v, b2h.v, acc0, 0, 0, 0);
    acc1 = __builtin_amdgcn_mfma_f32_32x32x16_bf16(fr[3].v, b2h.v, acc1, 0, 0, 0);
    acc0 = __builtin_amdgcn_mfma_f32_32x32x16_bf16(fr[0].v, b1l.v, acc0, 0, 0, 0);
    acc1 = __builtin_amdgcn_mfma_f32_32x32x16_bf16(fr[2].v, b1l.v, acc1, 0, 0, 0);
    acc0 = __builtin_amdgcn_mfma_f32_32x32x16_bf16(fr[1].v, b2l.v, acc0, 0, 0, 0);
    acc1 = __builtin_amdgcn_mfma_f32_32x32x16_bf16(fr[3].v, b2l.v, acc1, 0, 0, 0);
    acc0 = __builtin_amdgcn_mfma_f32_32x32x16_bf16(fr[4].v, b1h.v, acc0, 0, 0, 0);
    acc1 = __builtin_amdgcn_mfma_f32_32x32x16_bf16(fr[6].v, b1h.v, acc1, 0, 0, 0);
    acc0 = __builtin_amdgcn_mfma_f32_32x32x16_bf16(fr[5].v, b2h.v, acc0, 0, 0, 0);
    acc1 = __builtin_amdgcn_mfma_f32_32x32x16_bf16(fr[7].v, b2h.v, acc1, 0, 0, 0);
    #pragma unroll
    for (int r = 0; r < 16; ++r) d[r] = fmaf(xv.y, acc1[r], xv.x * acc0[r]);
}

__device__ __forceinline__ void issue_tile(const int* tb, int* slot, int lane) {
    #pragma unroll
    for (int f = 0; f < 8; ++f)
        __builtin_amdgcn_global_load_lds((gas_ptr)(tb + f * 256 + lane * 4),
                                         (las_ptr)(slot + f * 256), 16, 0, 0);
}

// ---- stage 1: per (side,b,group) wave computes the group transfer product ----
__global__ __launch_bounds__(256) void stage1(
    const float* __restrict__ x, const int* __restrict__ aprep,
    float* __restrict__ qws) {
    __shared__ int ring[4][2][2048];        // 64 KB: per-wave 2-slot tile ring
    __shared__ float2 xls[4][28];
    const int wv = threadIdx.x >> 6;
    const int w = blockIdx.x * 4 + wv;      // task 0..4095
    const int lane = threadIdx.x & 63;
    const int side = w >> 11;
    const int b = (w >> 4) & 127;
    const int g = w & 15;
    const int a = g * 24 + (g < 7 ? g : 7);
    const int len = 24 + (g < 7 ? 1 : 0);
    const int h = lane >> 5, col = lane & 31;
    const bool h0 = (h == 0);

    const float2* xb2 = (const float2*)x + b * 784;
    if (lane < len)
        xls[wv][lane] = side ? xb2[392 + a + lane] : xb2[a + len - lane];

    float d[16];
    #pragma unroll
    for (int r = 0; r < 16; ++r)
        d[r] = (((r & 3) + 8 * (r >> 2) + 4 * h) == col) ? 1.0f : 0.0f;   // Q = I

    const int* tbase = aprep + (size_t)side * NSTEP * 2048;
    // tile address for logical step j (clamped so prefetch never goes OOB)
    auto taddr = [&](int j) {
        int t = side ? (a + j) : (a + len - 1 - j);
        t = t < 0 ? 0 : (t > 390 ? 390 : t);
        return tbase + (size_t)t * 2048;
    };

    issue_tile(taddr(0), ring[wv][0], lane);
    issue_tile(taddr(1), ring[wv][1], lane);

    for (int j = 0; j < len; ++j) {
        int* slot = ring[wv][j & 1];
        W4S8 b1h, b2h, b1l, b2l;
        bpack(d, h0, b1h, b2h, b1l, b2l);   // depends only on d: overlaps loads
        WAITVM(8);                           // tile j landed (j+1 still in flight)
        I4S8 fr[8];
        #pragma unroll
        for (int f = 0; f < 8; ++f)
            fr[f].i = *(const int4*)(slot + f * 256 + lane * 4);
        LGKM0;                               // reads done before slot reuse
        issue_tile(taddr(j + 2), slot, lane);
        mstep(d, fr, b1h, b2h, b1l, b2l, xls[wv][j]);
    }
    WAITVM(0);   // drain dummy prefetches before LDS can be reallocated

    float4* qout = (float4*)(qws + (size_t)w * 1024 + lane * 16);
    qout[0] = make_float4(d[0], d[1], d[2], d[3]);
    qout[1] = make_float4(d[4], d[5], d[6], d[7]);
    qout[2] = make_float4(d[8], d[9], d[10], d[11]);
    qout[3] = make_float4(d[12], d[13], d[14], d[15]);
}

// ---- stage 2: v^T through the NGRP group matrices ----
__global__ __launch_bounds__(64) void stage2(
    const float* __restrict__ x, const float* __restrict__ a0,
    const float* __restrict__ aend, const float* __restrict__ qws,
    float* __restrict__ lw, float* __restrict__ rw) {
    const int b = blockIdx.x >> 1, side = blockIdx.x & 1;
    const int lane = threadIdx.x;
    const int j = lane >> 5, c = lane & 31;
    const float2* xb = (const float2*)x + b * 784;
    float v;
    if (side == 0) { float2 x0 = xb[0];   v = fmaf(a0[c * 2], x0.x, a0[c * 2 + 1] * x0.y); }
    else           { float2 xe = xb[783]; v = fmaf(aend[c * 2], xe.x, aend[c * 2 + 1] * xe.y); }
    for (int i = 0; i < NGRP; ++i) {
        const int g = side ? (NGRP - 1 - i) : i;
        const int task = side * 2048 + b * 16 + g;
        const float4* qp = (const float4*)(qws + (size_t)task * 1024 + (j * 32 + c) * 16);
        float q[16];
        #pragma unroll
        for (int u = 0; u < 4; ++u) {
            float4 t4 = qp[u];
            q[4 * u] = t4.x; q[4 * u + 1] = t4.y; q[4 * u + 2] = t4.z; q[4 * u + 3] = t4.w;
        }
        float s0 = 0.f, s1 = 0.f, s2 = 0.f, s3 = 0.f;
        #pragma unroll
        for (int r = 0; r < 16; r += 4) {
            s0 = fmaf(__shfl(v, 0 + 8 * (r >> 2) + 4 * j, 64), q[r + 0], s0);
            s1 = fmaf(__shfl(v, 1 + 8 * (r >> 2) + 4 * j, 64), q[r + 1], s1);
            s2 = fmaf(__shfl(v, 2 + 8 * (r >> 2) + 4 * j, 64), q[r + 2], s2);
            s3 = fmaf(__shfl(v, 3 + 8 * (r >> 2) + 4 * j, 64), q[r + 3], s3);
        }
        float s = (s0 + s1) + (s2 + s3);
        s += __shfl_xor(s, 32);
        v = s;
    }
    if (lane < 32) { (side ? rw : lw)[b * 32 + c] = v; }
}

__global__ __launch_bounds__(64) void mps_final(
    const float* __restrict__ lw, const float* __restrict__ rw,
    const float* __restrict__ mid,  // core_mid (32, 10, 32)
    float* __restrict__ out) {      // (B, 10)
    const int b = blockIdx.x;
    const int a = threadIdx.x & 31;
    float pa = lw[b * 32 + a] * rw[b * 32 + a];
    #pragma unroll
    for (int c = 0; c < 10; ++c) {
        float s = pa * mid[a * 320 + c * 32 + a];   // mid_diag[a,c] = core_mid[a,c,a]
        s += __shfl_xor(s, 16, 32);
        s += __shfl_xor(s, 8, 32);
        s += __shfl_xor(s, 4, 32);
        s += __shfl_xor(s, 2, 32);
        s += __shfl_xor(s, 1, 32);
        if (threadIdx.x == 0) out[b * 10 + c] = s;
    }
}

extern "C" void kernel_launch(void* const* d_in, const int* in_sizes, int n_in,
                              void* d_out, int out_size, void* d_ws, size_t ws_size,
                              hipStream_t stream) {
    const float* x      = (const float*)d_in[0];
    const float* a0     = (const float*)d_in[1];
    const float* coresL = (const float*)d_in[2];
    const float* mid    = (const float*)d_in[3];
    const float* coresR = (const float*)d_in[4];
    const float* aend   = (const float*)d_in[5];

    int*   aprep = (int*)d_ws;                           // 2*391*2048 dwords = 6.4 MB
    float* qws   = (float*)d_ws + 2 * NSTEP * 2048;      // 4096*1024 f32    = 16.8 MB
    float* lw    = qws + 4096 * 1024;
    float* rw    = lw + NB * 32;
    float* out   = (float*)d_out;

    prep<<<dim3(2 * NSTEP), dim3(256), 0, stream>>>(coresL, coresR, aprep);
    stage1<<<dim3(1024), dim3(256), 0, stream>>>(x, aprep, qws);
    stage2<<<dim3(2 * NB), dim3(64), 0, stream>>>(x, a0, aend, qws, lw, rw);
    mps_final<<<dim3(NB), dim3(64), 0, stream>>>(lw, rw, mid, out);
}

// Round 7
// 72.614 us; speedup vs baseline: 2.6525x; 1.2170x over previous
//
#include <hip/hip_runtime.h>

#define NSTEP 391
#define NB 128
#define NGRP 16

typedef __attribute__((ext_vector_type(8))) short s8v;      // 8 bf16 (4 VGPR)
typedef __attribute__((ext_vector_type(16))) float f32x16;  // MFMA C/D

typedef const __attribute__((address_space(1))) void* gas_ptr;
typedef __attribute__((address_space(3))) void* las_ptr;

union I4S8 { int4 i; s8v v; };
union W4S8 { int w[4]; s8v v; };

#define WAITVM(N) do { asm volatile("s_waitcnt vmcnt(" #N ")" ::: "memory"); \
                       __builtin_amdgcn_sched_barrier(0); } while (0)
#define LGKM0     do { asm volatile("s_waitcnt lgkmcnt(0)" ::: "memory");   \
                       __builtin_amdgcn_sched_barrier(0); } while (0)

__device__ __forceinline__ int pack_hi(float a, float b) {
    // word = [bf16(b)|bf16(a)], truncation
    return (__float_as_int(b) & 0xffff0000) | ((unsigned)__float_as_int(a) >> 16);
}
__device__ __forceinline__ float trunc_bf(float a) {
    return __int_as_float(__float_as_int(a) & 0xffff0000);
}
__device__ __forceinline__ int cvtpk(float a, float b) {  // [bf16(b)|bf16(a)] RNE
    int r;
    asm("v_cvt_pk_bf16_f32 %0, %1, %2" : "=v"(r) : "v"(a), "v"(b));
    return r;
}

// ---- prep: split A0/A1 into bf16 hi/lo MFMA A-fragments, frag-major tiles ----
// (verbatim from R6 — proven)
__global__ __launch_bounds__(256) void prep(
    const float* __restrict__ coresL, const float* __restrict__ coresR,
    int* __restrict__ aprep) {
    const int bid = blockIdx.x;            // 0..781
    const int side = bid >= NSTEP;
    const int t = bid - side * NSTEP;
    const float* st = (side ? coresR : coresL) + t * 2048;
    int* out = aprep + (size_t)(side * NSTEP + t) * 2048;
    for (int o = threadIdx.x; o < 2048; o += 256) {
        const int f = o >> 8, lane = (o >> 2) & 63, w = o & 3;
        const int part = f >> 2, p = (f >> 1) & 1, j = f & 1;
        const int h = lane >> 5, c = lane & 31;
        const int k0 = j * 16 + h * 8 + w * 2;
        float e0, e1;
        if (!side) { e0 = st[c * 64 + p * 32 + k0];  e1 = st[c * 64 + p * 32 + k0 + 1]; }
        else       { e0 = st[k0 * 64 + p * 32 + c];  e1 = st[(k0 + 1) * 64 + p * 32 + c]; }
        out[o] = (part == 0) ? pack_hi(e0, e1)
                             : pack_hi(e0 - trunc_bf(e0), e1 - trunc_bf(e1));
    }
}

// Build B-operand fragments from Q (C-layout f32 d[16]).
// Fast path: 8 v_perm + 8 permlane32_swap (pairs (q, q+2) swap to give
// words w[q] and w[q+2] directly — verified against the R4-proven selects).
__device__ __forceinline__ void bpack(const float* d, bool h0, W4S8& b1h, W4S8& b2h,
                                      W4S8& b1l, W4S8& b2l) {
#if __has_builtin(__builtin_amdgcn_permlane32_swap)
    int hw[8], lw[8];
    #pragma unroll
    for (int q = 0; q < 8; ++q) {
        float e = d[2 * q], o = d[2 * q + 1];
        hw[q] = __builtin_amdgcn_perm(__float_as_uint(o), __float_as_uint(e), 0x07060302u);
        lw[q] = cvtpk(e - trunc_bf(e), o - trunc_bf(o));
    }
    {
        auto r0 = __builtin_amdgcn_permlane32_swap(hw[0], hw[2], false, false);
        b1h.w[0] = r0[0]; b1h.w[2] = r0[1];
        auto r1 = __builtin_amdgcn_permlane32_swap(hw[1], hw[3], false, false);
        b1h.w[1] = r1[0]; b1h.w[3] = r1[1];
        auto r2 = __builtin_amdgcn_permlane32_swap(hw[4], hw[6], false, false);
        b2h.w[0] = r2[0]; b2h.w[2] = r2[1];
        auto r3 = __builtin_amdgcn_permlane32_swap(hw[5], hw[7], false, false);
        b2h.w[1] = r3[0]; b2h.w[3] = r3[1];
        auto r4 = __builtin_amdgcn_permlane32_swap(lw[0], lw[2], false, false);
        b1l.w[0] = r4[0]; b1l.w[2] = r4[1];
        auto r5 = __builtin_amdgcn_permlane32_swap(lw[1], lw[3], false, false);
        b1l.w[1] = r5[0]; b1l.w[3] = r5[1];
        auto r6 = __builtin_amdgcn_permlane32_swap(lw[4], lw[6], false, false);
        b2l.w[0] = r6[0]; b2l.w[2] = r6[1];
        auto r7 = __builtin_amdgcn_permlane32_swap(lw[5], lw[7], false, false);
        b2l.w[1] = r7[0]; b2l.w[3] = r7[1];
    }
    (void)h0;
#else
    float sx[16];
    #pragma unroll
    for (int r = 0; r < 16; ++r) sx[r] = __shfl_xor(d[r], 32);
    float B1[8], B2[8];
    #pragma unroll
    for (int m = 0; m < 4; ++m) {
        B1[m]     = h0 ? d[m]      : sx[4 + m];
        B1[4 + m] = h0 ? sx[m]     : d[4 + m];
        B2[m]     = h0 ? d[8 + m]  : sx[12 + m];
        B2[4 + m] = h0 ? sx[8 + m] : d[12 + m];
    }
    #pragma unroll
    for (int ww = 0; ww < 4; ++ww) {
        b1h.w[ww] = pack_hi(B1[2 * ww], B1[2 * ww + 1]);
        b2h.w[ww] = pack_hi(B2[2 * ww], B2[2 * ww + 1]);
        b1l.w[ww] = cvtpk(B1[2 * ww] - trunc_bf(B1[2 * ww]),
                          B1[2 * ww + 1] - trunc_bf(B1[2 * ww + 1]));
        b2l.w[ww] = cvtpk(B2[2 * ww] - trunc_bf(B2[2 * ww]),
                          B2[2 * ww + 1] - trunc_bf(B2[2 * ww + 1]));
    }
#endif
}

__device__ __forceinline__ void mstep(float* d, const I4S8* fr,
                                      const W4S8& b1h, const W4S8& b2h,
                                      const W4S8& b1l, const W4S8& b2l, float2 xv) {
    f32x16 acc0 = {}; f32x16 acc1 = {};
    acc0 = __builtin_amdgcn_mfma_f32_32x32x16_bf16(fr[0].v, b1h.v, acc0, 0, 0, 0);
    acc1 = __builtin_amdgcn_mfma_f32_32x32x16_bf16(fr[2].v, b1h.v, acc1, 0, 0, 0);
    acc0 = __builtin_amdgcn_mfma_f32_32x32x16_bf16(fr[1].v, b2h.v, acc0, 0, 0, 0);
    acc1 = __builtin_amdgcn_mfma_f32_32x32x16_bf16(fr[3].v, b2h.v, acc1, 0, 0, 0);
    acc0 = __builtin_amdgcn_mfma_f32_32x32x16_bf16(fr[0].v, b1l.v, acc0, 0, 0, 0);
    acc1 = __builtin_amdgcn_mfma_f32_32x32x16_bf16(fr[2].v, b1l.v, acc1, 0, 0, 0);
    acc0 = __builtin_amdgcn_mfma_f32_32x32x16_bf16(fr[1].v, b2l.v, acc0, 0, 0, 0);
    acc1 = __builtin_amdgcn_mfma_f32_32x32x16_bf16(fr[3].v, b2l.v, acc1, 0, 0, 0);
    acc0 = __builtin_amdgcn_mfma_f32_32x32x16_bf16(fr[4].v, b1h.v, acc0, 0, 0, 0);
    acc1 = __builtin_amdgcn_mfma_f32_32x32x16_bf16(fr[6].v, b1h.v, acc1, 0, 0, 0);
    acc0 = __builtin_amdgcn_mfma_f32_32x32x16_bf16(fr[5].v, b2h.v, acc0, 0, 0, 0);
    acc1 = __builtin_amdgcn_mfma_f32_32x32x16_bf16(fr[7].v, b2h.v, acc1, 0, 0, 0);
    #pragma unroll
    for (int r = 0; r < 16; ++r) d[r] = fmaf(xv.y, acc1[r], xv.x * acc0[r]);
}

__device__ __forceinline__ void issue_tile(const int* tb, int* slot, int lane) {
    #pragma unroll
    for (int f = 0; f < 8; ++f)
        __builtin_amdgcn_global_load_lds((gas_ptr)(tb + f * 256 + lane * 4),
                                         (las_ptr)(slot + f * 256), 16, 0, 0);
}

// ---- stage 1: per wave, ONE (side,g) tile-stream applied to TWO batch b's ----
__global__ __launch_bounds__(256) void stage1(
    const float* __restrict__ x, const int* __restrict__ aprep,
    float* __restrict__ qws) {
    __shared__ int ring[4][2][2048];        // 64 KB: per-wave 2-slot tile ring
    __shared__ float2 xls[4][2][28];
    const int wv = threadIdx.x >> 6;
    const int w = blockIdx.x * 4 + wv;      // wave task 0..2047
    const int lane = threadIdx.x & 63;
    const int side = w >> 10;
    const int g = (w >> 6) & 15;
    const int bp = w & 63;                  // batch pair: b0 = 2bp, b1 = 2bp+1
    const int a = g * 24 + (g < 7 ? g : 7);
    const int len = 24 + (g < 7 ? 1 : 0);
    const int h = lane >> 5, col = lane & 31;
    const bool h0 = (h == 0);

    const float2* xA = (const float2*)x + (bp * 2) * 784;
    const float2* xB = (const float2*)x + (bp * 2 + 1) * 784;
    if (lane < len) {
        int t = side ? (392 + a + lane) : (a + len - lane);
        xls[wv][0][lane] = xA[t];
        xls[wv][1][lane] = xB[t];
    }

    float d0[16], d1[16];
    #pragma unroll
    for (int r = 0; r < 16; ++r) {
        float iv = (((r & 3) + 8 * (r >> 2) + 4 * h) == col) ? 1.0f : 0.0f;  // Q = I
        d0[r] = iv; d1[r] = iv;
    }

    const int* tbase = aprep + (size_t)side * NSTEP * 2048;
    auto taddr = [&](int j) {
        int t = side ? (a + j) : (a + len - 1 - j);
        t = t < 0 ? 0 : (t > 390 ? 390 : t);
        return tbase + (size_t)t * 2048;
    };

    issue_tile(taddr(0), ring[wv][0], lane);
    issue_tile(taddr(1), ring[wv][1], lane);

    for (int j = 0; j < len; ++j) {
        int* slot = ring[wv][j & 1];
        W4S8 p1h, p2h, p1l, p2l, q1h, q2h, q1l, q2l;
        bpack(d0, h0, p1h, p2h, p1l, p2l);  // overlaps in-flight loads
        bpack(d1, h0, q1h, q2h, q1l, q2l);
        WAITVM(8);                           // tile j landed (j+1 in flight)
        I4S8 fr[8];
        #pragma unroll
        for (int f = 0; f < 8; ++f)
            fr[f].i = *(const int4*)(slot + f * 256 + lane * 4);
        mstep(d0, fr, p1h, p2h, p1l, p2l, xls[wv][0][j]);
        mstep(d1, fr, q1h, q2h, q1l, q2l, xls[wv][1][j]);
        LGKM0;                               // reads drained (free here)
        issue_tile(taddr(j + 2), slot, lane);
    }
    WAITVM(0);   // drain clamp prefetches before LDS can be reallocated

    float4* q0 = (float4*)(qws + (size_t)(side * 2048 + (bp * 2) * 16 + g) * 1024 + lane * 16);
    float4* q1 = (float4*)(qws + (size_t)(side * 2048 + (bp * 2 + 1) * 16 + g) * 1024 + lane * 16);
    q0[0] = make_float4(d0[0], d0[1], d0[2], d0[3]);
    q0[1] = make_float4(d0[4], d0[5], d0[6], d0[7]);
    q0[2] = make_float4(d0[8], d0[9], d0[10], d0[11]);
    q0[3] = make_float4(d0[12], d0[13], d0[14], d0[15]);
    q1[0] = make_float4(d1[0], d1[1], d1[2], d1[3]);
    q1[1] = make_float4(d1[4], d1[5], d1[6], d1[7]);
    q1[2] = make_float4(d1[8], d1[9], d1[10], d1[11]);
    q1[3] = make_float4(d1[12], d1[13], d1[14], d1[15]);
}

// ---- stage 2: v^T through the NGRP group matrices (verbatim R6) ----
__global__ __launch_bounds__(64) void stage2(
    const float* __restrict__ x, const float* __restrict__ a0,
    const float* __restrict__ aend, const float* __restrict__ qws,
    float* __restrict__ lw, float* __restrict__ rw) {
    const int b = blockIdx.x >> 1, side = blockIdx.x & 1;
    const int lane = threadIdx.x;
    const int j = lane >> 5, c = lane & 31;
    const float2* xb = (const float2*)x + b * 784;
    float v;
    if (side == 0) { float2 x0 = xb[0];   v = fmaf(a0[c * 2], x0.x, a0[c * 2 + 1] * x0.y); }
    else           { float2 xe = xb[783]; v = fmaf(aend[c * 2], xe.x, aend[c * 2 + 1] * xe.y); }
    for (int i = 0; i < NGRP; ++i) {
        const int g = side ? (NGRP - 1 - i) : i;
        const int task = side * 2048 + b * 16 + g;
        const float4* qp = (const float4*)(qws + (size_t)task * 1024 + (j * 32 + c) * 16);
        float q[16];
        #pragma unroll
        for (int u = 0; u < 4; ++u) {
            float4 t4 = qp[u];
            q[4 * u] = t4.x; q[4 * u + 1] = t4.y; q[4 * u + 2] = t4.z; q[4 * u + 3] = t4.w;
        }
        float s0 = 0.f, s1 = 0.f, s2 = 0.f, s3 = 0.f;
        #pragma unroll
        for (int r = 0; r < 16; r += 4) {
            s0 = fmaf(__shfl(v, 0 + 8 * (r >> 2) + 4 * j, 64), q[r + 0], s0);
            s1 = fmaf(__shfl(v, 1 + 8 * (r >> 2) + 4 * j, 64), q[r + 1], s1);
            s2 = fmaf(__shfl(v, 2 + 8 * (r >> 2) + 4 * j, 64), q[r + 2], s2);
            s3 = fmaf(__shfl(v, 3 + 8 * (r >> 2) + 4 * j, 64), q[r + 3], s3);
        }
        float s = (s0 + s1) + (s2 + s3);
        s += __shfl_xor(s, 32);
        v = s;
    }
    if (lane < 32) { (side ? rw : lw)[b * 32 + c] = v; }
}

__global__ __launch_bounds__(64) void mps_final(
    const float* __restrict__ lw, const float* __restrict__ rw,
    const float* __restrict__ mid,  // core_mid (32, 10, 32)
    float* __restrict__ out) {      // (B, 10)
    const int b = blockIdx.x;
    const int a = threadIdx.x & 31;
    float pa = lw[b * 32 + a] * rw[b * 32 + a];
    #pragma unroll
    for (int c = 0; c < 10; ++c) {
        float s = pa * mid[a * 320 + c * 32 + a];   // mid_diag[a,c] = core_mid[a,c,a]
        s += __shfl_xor(s, 16, 32);
        s += __shfl_xor(s, 8, 32);
        s += __shfl_xor(s, 4, 32);
        s += __shfl_xor(s, 2, 32);
        s += __shfl_xor(s, 1, 32);
        if (threadIdx.x == 0) out[b * 10 + c] = s;
    }
}

extern "C" void kernel_launch(void* const* d_in, const int* in_sizes, int n_in,
                              void* d_out, int out_size, void* d_ws, size_t ws_size,
                              hipStream_t stream) {
    const float* x      = (const float*)d_in[0];
    const float* a0     = (const float*)d_in[1];
    const float* coresL = (const float*)d_in[2];
    const float* mid    = (const float*)d_in[3];
    const float* coresR = (const float*)d_in[4];
    const float* aend   = (const float*)d_in[5];

    int*   aprep = (int*)d_ws;                           // 2*391*2048 dwords = 6.4 MB
    float* qws   = (float*)d_ws + 2 * NSTEP * 2048;      // 4096*1024 f32    = 16.8 MB
    float* lw    = qws + 4096 * 1024;
    float* rw    = lw + NB * 32;
    float* out   = (float*)d_out;

    prep<<<dim3(2 * NSTEP), dim3(256), 0, stream>>>(coresL, coresR, aprep);
    stage1<<<dim3(512), dim3(256), 0, stream>>>(x, aprep, qws);
    stage2<<<dim3(2 * NB), dim3(64), 0, stream>>>(x, a0, aend, qws, lw, rw);
    mps_final<<<dim3(NB), dim3(64), 0, stream>>>(lw, rw, mid, out);
}

// Round 8
// 67.263 us; speedup vs baseline: 2.8635x; 1.0795x over previous
//
#include <hip/hip_runtime.h>

#define NSTEP 391
#define NB 128
#define NGRP 16

typedef __attribute__((ext_vector_type(8))) short s8v;      // 8 bf16 (4 VGPR)
typedef __attribute__((ext_vector_type(16))) float f32x16;  // MFMA C/D

typedef const __attribute__((address_space(1))) void* gas_ptr;
typedef __attribute__((address_space(3))) void* las_ptr;

union I4S8 { int4 i; s8v v; };
union W4S8 { int w[4]; s8v v; };

#define WAITVM(N) do { asm volatile("s_waitcnt vmcnt(" #N ")" ::: "memory"); \
                       __builtin_amdgcn_sched_barrier(0); } while (0)
#define LGKM0     do { asm volatile("s_waitcnt lgkmcnt(0)" ::: "memory");   \
                       __builtin_amdgcn_sched_barrier(0); } while (0)
#define SBAR      do { __builtin_amdgcn_s_barrier();                        \
                       __builtin_amdgcn_sched_barrier(0); } while (0)

__device__ __forceinline__ int pack_hi(float a, float b) {
    // word = [bf16(b)|bf16(a)], truncation
    return (__float_as_int(b) & 0xffff0000) | ((unsigned)__float_as_int(a) >> 16);
}
__device__ __forceinline__ float trunc_bf(float a) {
    return __int_as_float(__float_as_int(a) & 0xffff0000);
}
__device__ __forceinline__ int cvtpk(float a, float b) {  // [bf16(b)|bf16(a)] RNE
    int r;
    asm("v_cvt_pk_bf16_f32 %0, %1, %2" : "=v"(r) : "v"(a), "v"(b));
    return r;
}

// ---- prep: split A0/A1 into bf16 hi/lo MFMA A-fragments, frag-major tiles ----
// (verbatim R6/R7 — proven)
__global__ __launch_bounds__(256) void prep(
    const float* __restrict__ coresL, const float* __restrict__ coresR,
    int* __restrict__ aprep) {
    const int bid = blockIdx.x;            // 0..781
    const int side = bid >= NSTEP;
    const int t = bid - side * NSTEP;
    const float* st = (side ? coresR : coresL) + t * 2048;
    int* out = aprep + (size_t)(side * NSTEP + t) * 2048;
    for (int o = threadIdx.x; o < 2048; o += 256) {
        const int f = o >> 8, lane = (o >> 2) & 63, w = o & 3;
        const int part = f >> 2, p = (f >> 1) & 1, j = f & 1;
        const int h = lane >> 5, c = lane & 31;
        const int k0 = j * 16 + h * 8 + w * 2;
        float e0, e1;
        if (!side) { e0 = st[c * 64 + p * 32 + k0];  e1 = st[c * 64 + p * 32 + k0 + 1]; }
        else       { e0 = st[k0 * 64 + p * 32 + c];  e1 = st[(k0 + 1) * 64 + p * 32 + c]; }
        out[o] = (part == 0) ? pack_hi(e0, e1)
                             : pack_hi(e0 - trunc_bf(e0), e1 - trunc_bf(e1));
    }
}

// Build B-operand fragments from Q (C-layout f32 d[16]).  (proven R7)
__device__ __forceinline__ void bpack(const float* d, bool h0, W4S8& b1h, W4S8& b2h,
                                      W4S8& b1l, W4S8& b2l) {
#if __has_builtin(__builtin_amdgcn_permlane32_swap)
    int hw[8], lw[8];
    #pragma unroll
    for (int q = 0; q < 8; ++q) {
        float e = d[2 * q], o = d[2 * q + 1];
        hw[q] = __builtin_amdgcn_perm(__float_as_uint(o), __float_as_uint(e), 0x07060302u);
        lw[q] = cvtpk(e - trunc_bf(e), o - trunc_bf(o));
    }
    {
        auto r0 = __builtin_amdgcn_permlane32_swap(hw[0], hw[2], false, false);
        b1h.w[0] = r0[0]; b1h.w[2] = r0[1];
        auto r1 = __builtin_amdgcn_permlane32_swap(hw[1], hw[3], false, false);
        b1h.w[1] = r1[0]; b1h.w[3] = r1[1];
        auto r2 = __builtin_amdgcn_permlane32_swap(hw[4], hw[6], false, false);
        b2h.w[0] = r2[0]; b2h.w[2] = r2[1];
        auto r3 = __builtin_amdgcn_permlane32_swap(hw[5], hw[7], false, false);
        b2h.w[1] = r3[0]; b2h.w[3] = r3[1];
        auto r4 = __builtin_amdgcn_permlane32_swap(lw[0], lw[2], false, false);
        b1l.w[0] = r4[0]; b1l.w[2] = r4[1];
        auto r5 = __builtin_amdgcn_permlane32_swap(lw[1], lw[3], false, false);
        b1l.w[1] = r5[0]; b1l.w[3] = r5[1];
        auto r6 = __builtin_amdgcn_permlane32_swap(lw[4], lw[6], false, false);
        b2l.w[0] = r6[0]; b2l.w[2] = r6[1];
        auto r7 = __builtin_amdgcn_permlane32_swap(lw[5], lw[7], false, false);
        b2l.w[1] = r7[0]; b2l.w[3] = r7[1];
    }
    (void)h0;
#else
    float sx[16];
    #pragma unroll
    for (int r = 0; r < 16; ++r) sx[r] = __shfl_xor(d[r], 32);
    float B1[8], B2[8];
    #pragma unroll
    for (int m = 0; m < 4; ++m) {
        B1[m]     = h0 ? d[m]      : sx[4 + m];
        B1[4 + m] = h0 ? sx[m]     : d[4 + m];
        B2[m]     = h0 ? d[8 + m]  : sx[12 + m];
        B2[4 + m] = h0 ? sx[8 + m] : d[12 + m];
    }
    #pragma unroll
    for (int ww = 0; ww < 4; ++ww) {
        b1h.w[ww] = pack_hi(B1[2 * ww], B1[2 * ww + 1]);
        b2h.w[ww] = pack_hi(B2[2 * ww], B2[2 * ww + 1]);
        b1l.w[ww] = cvtpk(B1[2 * ww] - trunc_bf(B1[2 * ww]),
                          B1[2 * ww + 1] - trunc_bf(B1[2 * ww + 1]));
        b2l.w[ww] = cvtpk(B2[2 * ww] - trunc_bf(B2[2 * ww]),
                          B2[2 * ww + 1] - trunc_bf(B2[2 * ww + 1]));
    }
#endif
}

__device__ __forceinline__ void mstep(float* d, const I4S8* fr,
                                      const W4S8& b1h, const W4S8& b2h,
                                      const W4S8& b1l, const W4S8& b2l, float2 xv) {
    f32x16 acc0 = {}; f32x16 acc1 = {};
    acc0 = __builtin_amdgcn_mfma_f32_32x32x16_bf16(fr[0].v, b1h.v, acc0, 0, 0, 0);
    acc1 = __builtin_amdgcn_mfma_f32_32x32x16_bf16(fr[2].v, b1h.v, acc1, 0, 0, 0);
    acc0 = __builtin_amdgcn_mfma_f32_32x32x16_bf16(fr[1].v, b2h.v, acc0, 0, 0, 0);
    acc1 = __builtin_amdgcn_mfma_f32_32x32x16_bf16(fr[3].v, b2h.v, acc1, 0, 0, 0);
    acc0 = __builtin_amdgcn_mfma_f32_32x32x16_bf16(fr[0].v, b1l.v, acc0, 0, 0, 0);
    acc1 = __builtin_amdgcn_mfma_f32_32x32x16_bf16(fr[2].v, b1l.v, acc1, 0, 0, 0);
    acc0 = __builtin_amdgcn_mfma_f32_32x32x16_bf16(fr[1].v, b2l.v, acc0, 0, 0, 0);
    acc1 = __builtin_amdgcn_mfma_f32_32x32x16_bf16(fr[3].v, b2l.v, acc1, 0, 0, 0);
    acc0 = __builtin_amdgcn_mfma_f32_32x32x16_bf16(fr[4].v, b1h.v, acc0, 0, 0, 0);
    acc1 = __builtin_amdgcn_mfma_f32_32x32x16_bf16(fr[6].v, b1h.v, acc1, 0, 0, 0);
    acc0 = __builtin_amdgcn_mfma_f32_32x32x16_bf16(fr[5].v, b2h.v, acc0, 0, 0, 0);
    acc1 = __builtin_amdgcn_mfma_f32_32x32x16_bf16(fr[7].v, b2h.v, acc1, 0, 0, 0);
    #pragma unroll
    for (int r = 0; r < 16; ++r) d[r] = fmaf(xv.y, acc1[r], xv.x * acc0[r]);
}

// each wave issues its 2 of the 8 frag-loads of one tile into the shared slot
__device__ __forceinline__ void issue_part(const int* tb, int* slot, int lane, int wv) {
    const int f0 = wv * 2;
    __builtin_amdgcn_global_load_lds((gas_ptr)(tb + f0 * 256 + lane * 4),
                                     (las_ptr)(slot + f0 * 256), 16, 0, 0);
    __builtin_amdgcn_global_load_lds((gas_ptr)(tb + (f0 + 1) * 256 + lane * 4),
                                     (las_ptr)(slot + (f0 + 1) * 256), 16, 0, 0);
}

// ---- stage 1: block = 4 waves on ONE (side,g) stream, shared 2-slot ring, ----
// ---- one batch element per wave, 4 blocks/CU (4 waves/SIMD).              ----
__global__ __launch_bounds__(256, 4) void stage1(
    const float* __restrict__ x, const int* __restrict__ aprep,
    float* __restrict__ qws) {
    __shared__ int ring[2][2048];           // 16 KB shared tile ring
    __shared__ float2 xls[4][28];
    const int wv = threadIdx.x >> 6;
    const int lane = threadIdx.x & 63;
    // XCD co-location: dispatch d -> xcd = d&7 (round-robin heuristic).
    // stream (side,g) fixed per (xcd, stream_local): 4 streams per XCD.
    const int dsp = blockIdx.x;             // 0..1023
    const int xcd = dsp & 7;
    const int s = dsp >> 3;                 // 0..127
    const int stream = xcd + 8 * (s & 3);   // 0..31
    const int inb = s >> 2;                 // 0..31
    const int side = stream >> 4;
    const int g = stream & 15;
    const int b = inb * 4 + wv;             // this wave's batch element
    const int a = g * 24 + (g < 7 ? g : 7);
    const int len = 24 + (g < 7 ? 1 : 0);
    const int h = lane >> 5, col = lane & 31;
    const bool h0 = (h == 0);

    const float2* xb2 = (const float2*)x + b * 784;
    if (lane < len) {
        int t = side ? (392 + a + lane) : (a + len - lane);
        xls[wv][lane] = xb2[t];
    }

    float d0[16];
    #pragma unroll
    for (int r = 0; r < 16; ++r)
        d0[r] = (((r & 3) + 8 * (r >> 2) + 4 * h) == col) ? 1.0f : 0.0f;  // Q = I

    const int* tbase = aprep + (size_t)side * NSTEP * 2048;
    auto taddr = [&](int j) {
        int t = side ? (a + j) : (a + len - 1 - j);
        t = t < 0 ? 0 : (t > 390 ? 390 : t);
        return tbase + (size_t)t * 2048;
    };

    issue_part(taddr(0), ring[0], lane, wv);
    issue_part(taddr(1), ring[1], lane, wv);

    for (int j = 0; j < len; ++j) {
        int* slot = ring[j & 1];
        W4S8 b1h, b2h, b1l, b2l;
        bpack(d0, h0, b1h, b2h, b1l, b2l);  // overlaps in-flight loads
        WAITVM(2);                           // own 2 loads of tile j landed
        SBAR;                                // all waves' parts landed -> tile ready
        I4S8 fr[8];
        #pragma unroll
        for (int f = 0; f < 8; ++f)
            fr[f].i = *(const int4*)(slot + f * 256 + lane * 4);
        mstep(d0, fr, b1h, b2h, b1l, b2l, xls[wv][j]);
        LGKM0;                               // own reads of slot done
        SBAR;                                // all waves done reading -> slot free
        issue_part(taddr(j + 2), slot, lane, wv);
    }
    WAITVM(0);   // drain clamp prefetches before LDS can be reallocated

    float4* q0 = (float4*)(qws + (size_t)(side * 2048 + b * 16 + g) * 1024 + lane * 16);
    q0[0] = make_float4(d0[0], d0[1], d0[2], d0[3]);
    q0[1] = make_float4(d0[4], d0[5], d0[6], d0[7]);
    q0[2] = make_float4(d0[8], d0[9], d0[10], d0[11]);
    q0[3] = make_float4(d0[12], d0[13], d0[14], d0[15]);
}

// ---- stage 2: v^T through the NGRP group matrices (verbatim) ----
__global__ __launch_bounds__(64) void stage2(
    const float* __restrict__ x, const float* __restrict__ a0,
    const float* __restrict__ aend, const float* __restrict__ qws,
    float* __restrict__ lw, float* __restrict__ rw) {
    const int b = blockIdx.x >> 1, side = blockIdx.x & 1;
    const int lane = threadIdx.x;
    const int j = lane >> 5, c = lane & 31;
    const float2* xb = (const float2*)x + b * 784;
    float v;
    if (side == 0) { float2 x0 = xb[0];   v = fmaf(a0[c * 2], x0.x, a0[c * 2 + 1] * x0.y); }
    else           { float2 xe = xb[783]; v = fmaf(aend[c * 2], xe.x, aend[c * 2 + 1] * xe.y); }
    for (int i = 0; i < NGRP; ++i) {
        const int g = side ? (NGRP - 1 - i) : i;
        const int task = side * 2048 + b * 16 + g;
        const float4* qp = (const float4*)(qws + (size_t)task * 1024 + (j * 32 + c) * 16);
        float q[16];
        #pragma unroll
        for (int u = 0; u < 4; ++u) {
            float4 t4 = qp[u];
            q[4 * u] = t4.x; q[4 * u + 1] = t4.y; q[4 * u + 2] = t4.z; q[4 * u + 3] = t4.w;
        }
        float s0 = 0.f, s1 = 0.f, s2 = 0.f, s3 = 0.f;
        #pragma unroll
        for (int r = 0; r < 16; r += 4) {
            s0 = fmaf(__shfl(v, 0 + 8 * (r >> 2) + 4 * j, 64), q[r + 0], s0);
            s1 = fmaf(__shfl(v, 1 + 8 * (r >> 2) + 4 * j, 64), q[r + 1], s1);
            s2 = fmaf(__shfl(v, 2 + 8 * (r >> 2) + 4 * j, 64), q[r + 2], s2);
            s3 = fmaf(__shfl(v, 3 + 8 * (r >> 2) + 4 * j, 64), q[r + 3], s3);
        }
        float s = (s0 + s1) + (s2 + s3);
        s += __shfl_xor(s, 32);
        v = s;
    }
    if (lane < 32) { (side ? rw : lw)[b * 32 + c] = v; }
}

__global__ __launch_bounds__(64) void mps_final(
    const float* __restrict__ lw, const float* __restrict__ rw,
    const float* __restrict__ mid,  // core_mid (32, 10, 32)
    float* __restrict__ out) {      // (B, 10)
    const int b = blockIdx.x;
    const int a = threadIdx.x & 31;
    float pa = lw[b * 32 + a] * rw[b * 32 + a];
    #pragma unroll
    for (int c = 0; c < 10; ++c) {
        float s = pa * mid[a * 320 + c * 32 + a];   // mid_diag[a,c] = core_mid[a,c,a]
        s += __shfl_xor(s, 16, 32);
        s += __shfl_xor(s, 8, 32);
        s += __shfl_xor(s, 4, 32);
        s += __shfl_xor(s, 2, 32);
        s += __shfl_xor(s, 1, 32);
        if (threadIdx.x == 0) out[b * 10 + c] = s;
    }
}

extern "C" void kernel_launch(void* const* d_in, const int* in_sizes, int n_in,
                              void* d_out, int out_size, void* d_ws, size_t ws_size,
                              hipStream_t stream) {
    const float* x      = (const float*)d_in[0];
    const float* a0     = (const float*)d_in[1];
    const float* coresL = (const float*)d_in[2];
    const float* mid    = (const float*)d_in[3];
    const float* coresR = (const float*)d_in[4];
    const float* aend   = (const float*)d_in[5];

    int*   aprep = (int*)d_ws;                           // 2*391*2048 dwords = 6.4 MB
    float* qws   = (float*)d_ws + 2 * NSTEP * 2048;      // 4096*1024 f32    = 16.8 MB
    float* lw    = qws + 4096 * 1024;
    float* rw    = lw + NB * 32;
    float* out   = (float*)d_out;

    prep<<<dim3(2 * NSTEP), dim3(256), 0, stream>>>(coresL, coresR, aprep);
    stage1<<<dim3(1024), dim3(256), 0, stream>>>(x, aprep, qws);
    stage2<<<dim3(2 * NB), dim3(64), 0, stream>>>(x, a0, aend, qws, lw, rw);
    mps_final<<<dim3(NB), dim3(64), 0, stream>>>(lw, rw, mid, out);
}